// Round 5
// baseline (436.980 us; speedup 1.0000x reference)
//
#include <hip/hip_runtime.h>
#include <cmath>

// CausalSelfAttention fused pipeline, MI355X/gfx950.
// R14: GEMM core rebuilt as a 3-buffer counted-vmcnt pipeline (T3/T4):
//   stage tile t+2 | s_waitcnt vmcnt(16) | s_barrier | compute buf[t%3]
//   | lgkmcnt(0)+sched_barrier | s_barrier.  Loads never drain to 0 in the
//   main loop (raw s_barrier, NOT __syncthreads which force-emits vmcnt(0)).
//   Geometry/fragments/epilogue identical to the verified 128x128 core.
// attn: R13 body + T13 defer-max (THR=8, skip O-rescale unless max grew >8).
// Everything else unchanged from R13 (372.4 us).

#define S_LEN 2048
#define DMODEL 2048
#define NH 16
#define NKV 4
#define HD 128

#define NEG_SENT -1.0e30f
#define QK_SCALE 0.08838834764831845f  // 1/sqrt(128), folded into Q
#define RESCALE_THR 8.0f               // T13 defer-max threshold

typedef _Float16 f16x8 __attribute__((ext_vector_type(8)));
typedef float f32x4 __attribute__((ext_vector_type(4)));

static __device__ __forceinline__ short f2h(float f) {
  _Float16 h = (_Float16)f;
  return *(short*)&h;
}
static __device__ __forceinline__ float h2f(short s) {
  _Float16 h = *(_Float16*)&s;
  return (float)h;
}

// async global->LDS, 16B per lane; lds dst = wave-uniform base + lane*16.
static __device__ __forceinline__ void stage16(const short* g, short* ldsbase) {
  __builtin_amdgcn_global_load_lds(
      (const __attribute__((address_space(1))) void*)g,
      (__attribute__((address_space(3))) void*)ldsbase, 16, 0, 0);
}

// ---------------------------------------------------------------------------
// Fused fp32 -> fp16 convert for all five tensors in one launch.
// Segment sizes in float4 units (all multiples of 256 -> block-uniform
// branch): x 2097152 | q_w 1048576 | k_w 262144 | v_w 262144 | out_w 1048576
// ---------------------------------------------------------------------------
__global__ __launch_bounds__(256) void f32_to_f16_all(
    const float* __restrict__ s0, const float* __restrict__ s1,
    const float* __restrict__ s2, const float* __restrict__ s3,
    const float* __restrict__ s4, short* __restrict__ d0,
    short* __restrict__ d1, short* __restrict__ d2, short* __restrict__ d3,
    short* __restrict__ d4) {
  int u = blockIdx.x * 256 + threadIdx.x;  // float4 index
  const float* src;
  short* dst;
  int off;
  if (u < 2097152) {
    src = s0; dst = d0; off = u;
  } else if (u < 3145728) {
    src = s1; dst = d1; off = u - 2097152;
  } else if (u < 3407872) {
    src = s2; dst = d2; off = u - 3145728;
  } else if (u < 3670016) {
    src = s3; dst = d3; off = u - 3407872;
  } else {
    src = s4; dst = d4; off = u - 3670016;
  }
  float4 v = *reinterpret_cast<const float4*>(src + (size_t)off * 4);
  short4 o;
  o.x = f2h(v.x); o.y = f2h(v.y); o.z = f2h(v.z); o.w = f2h(v.w);
  *reinterpret_cast<short4*>(dst + (size_t)off * 4) = o;
}

// ---------------------------------------------------------------------------
// GEMM core, R14: C[M,N] = A[M,K] @ W[N,K]^T, fp16 in, fp32 accum.
// 128x128 tile, BK=64, 3-slot LDS ring (96KB), counted-vmcnt pipeline.
// Staging addresses identical to the verified core: wave w stages rows
// {w*8 + i*32 + lane/8}, cols (lane&7)*8 into unpadded [128][64] slots.
// vmcnt ledger (8 loads per thread per tile):
//   prologue: stage t0,t1 (16 outstanding)
//   iter t:   stage t+2 (24) -> vmcnt(16) retires tile t's 8
//   t=NT-2:   no stage      -> vmcnt(8)
//   t=NT-1:   no stage      -> vmcnt(0)
// Raw s_barrier (no implicit drain); lgkmcnt(0)+sched_barrier(0) before the
// end-of-tile barrier so no ds_read is outstanding when the slot is re-staged.
// ---------------------------------------------------------------------------
template <bool F32OUT>
static __device__ __forceinline__ void gemm_core(const short* __restrict__ A,
                                                 const short* __restrict__ W,
                                                 void* __restrict__ Cv,
                                                 int N, int K, int bm, int bn) {
  __shared__ __align__(16) short As[3][128][64];
  __shared__ __align__(16) short Ws[3][128][64];
  const int tid = threadIdx.x;
  const int wave = tid >> 6, lane = tid & 63;
  const int quad = lane >> 4, l16 = lane & 15;
  const int wm = (wave >> 1) * 64, wn = (wave & 1) * 64;

  f32x4 acc[4][4];
#pragma unroll
  for (int i = 0; i < 4; i++)
#pragma unroll
    for (int j = 0; j < 4; j++) acc[i][j] = f32x4{0.f, 0.f, 0.f, 0.f};

  const int srow = wave * 8 + (lane >> 3);  // staging row (this lane)
  const int scol = (lane & 7) * 8;          // staging col

  const int NT = K >> 6;  // K-tiles (K=2048 -> 32; always >= 2 here)

  auto stage_tile = [&](int t, int s) {
    const int k0 = t * 64;
#pragma unroll
    for (int i = 0; i < 4; i++) {
      stage16(A + (size_t)(bm + srow + i * 32) * K + k0 + scol,
              &As[s][wave * 8 + i * 32][0]);
      stage16(W + (size_t)(bn + srow + i * 32) * K + k0 + scol,
              &Ws[s][wave * 8 + i * 32][0]);
    }
  };

  stage_tile(0, 0);
  stage_tile(1, 1);

  for (int t = 0; t < NT; t++) {
    const int s = t % 3;
    if (t + 2 < NT) {
      stage_tile(t + 2, (t + 2) % 3);
      asm volatile("s_waitcnt vmcnt(16)" ::: "memory");
    } else if (t + 1 < NT) {
      asm volatile("s_waitcnt vmcnt(8)" ::: "memory");
    } else {
      asm volatile("s_waitcnt vmcnt(0)" ::: "memory");
    }
    __builtin_amdgcn_s_barrier();  // all waves' tile-t loads landed

#pragma unroll
    for (int kk = 0; kk < 64; kk += 32) {
      f16x8 af[4], bfr[4];
#pragma unroll
      for (int mi = 0; mi < 4; mi++)
        af[mi] = *reinterpret_cast<const f16x8*>(&As[s][wm + mi * 16 + l16][kk + quad * 8]);
#pragma unroll
      for (int ni = 0; ni < 4; ni++)
        bfr[ni] = *reinterpret_cast<const f16x8*>(&Ws[s][wn + ni * 16 + l16][kk + quad * 8]);
#pragma unroll
      for (int mi = 0; mi < 4; mi++)
#pragma unroll
        for (int ni = 0; ni < 4; ni++)
          acc[mi][ni] = __builtin_amdgcn_mfma_f32_16x16x32_f16(af[mi], bfr[ni], acc[mi][ni], 0, 0, 0);
    }

    if (t + 1 < NT) {
      // drain this tile's ds_reads before the slot can be re-staged (t+3)
      asm volatile("s_waitcnt lgkmcnt(0)" ::: "memory");
      __builtin_amdgcn_sched_barrier(0);
      __builtin_amdgcn_s_barrier();
    }
  }

  // C/D layout: row = quad*4 + r, col = l16
#pragma unroll
  for (int mi = 0; mi < 4; mi++)
#pragma unroll
    for (int ni = 0; ni < 4; ni++) {
      int gr = bm + wm + mi * 16 + quad * 4;
      int gc = bn + wn + ni * 16 + l16;
#pragma unroll
      for (int r = 0; r < 4; r++) {
        if (F32OUT)
          ((float*)Cv)[(size_t)(gr + r) * N + gc] = acc[mi][ni][r];
        else
          ((short*)Cv)[(size_t)(gr + r) * N + gc] = f2h(acc[mi][ni][r]);
      }
    }
}

template <bool F32OUT>
__global__ __launch_bounds__(256) void gemm_bt(const short* __restrict__ A,
                                               const short* __restrict__ W,
                                               void* __restrict__ Cv,
                                               int N, int K) {
  gemm_core<F32OUT>(A, W, Cv, N, K, blockIdx.x * 128, blockIdx.y * 128);
}

// Q, K, V projections in ONE launch. Grid (32, 24): y<16 -> Q (N=2048),
// y in [16,20) -> K, y in [20,24) -> V (N=512). Block-uniform branch.
__global__ __launch_bounds__(256) void gemm_qkv(const short* __restrict__ A,
                                                const short* __restrict__ Wq,
                                                const short* __restrict__ Wk,
                                                const short* __restrict__ Wv,
                                                short* __restrict__ Cq,
                                                short* __restrict__ Ck,
                                                short* __restrict__ Cvp,
                                                int K) {
  const int y = blockIdx.y;
  const short* W;
  short* C;
  int N, bn;
  if (y < 16) {
    W = Wq; C = Cq; N = 2048; bn = y * 128;
  } else if (y < 20) {
    W = Wk; C = Ck; N = 512; bn = (y - 16) * 128;
  } else {
    W = Wv; C = Cvp; N = 512; bn = (y - 20) * 128;
  }
  gemm_core<false>(A, W, (void*)C, N, K, blockIdx.x * 128, bn);
}

// ---------------------------------------------------------------------------
// Per-(token,head) RMSNorm + partial RoPE + optional gain, relayout to
// [b][head][s][128]. mode: 1=norm+rope(k), 2=norm+rope+gain*qk_scale(q).
// ---------------------------------------------------------------------------
__global__ __launch_bounds__(256) void postproc(const short* __restrict__ src,
                                                short* __restrict__ dst,
                                                const float* __restrict__ gain,
                                                int n_heads, int mode) {
  int gw = blockIdx.x * 4 + (threadIdx.x >> 6);
  int lane = threadIdx.x & 63;
  int head = gw % n_heads;
  int token = gw / n_heads;
  int s = token & (S_LEN - 1);
  int b = token >> 11;
  const short* sp = src + (size_t)token * (n_heads * HD) + head * HD;
  float v0 = h2f(sp[lane]);
  float v1 = h2f(sp[lane + 64]);
  float ss = v0 * v0 + v1 * v1;
#pragma unroll
  for (int off = 1; off < 64; off <<= 1) ss += __shfl_xor(ss, off, 64);
  float sc = rsqrtf(ss * (1.0f / 128.0f) + 1.1920929e-07f);
  v0 *= sc;
  v1 *= sc;
  int i = lane & 31;
  float inv = powf(10000.0f, -((float)(2 * i) * (1.0f / 64.0f)));
  float f = (float)s * inv;
  float cs, sn;
  sincosf(f, &sn, &cs);
  float partner = __shfl_xor(v0, 32, 64);
  v0 = (lane < 32) ? (v0 * cs + partner * sn) : (v0 * cs - partner * sn);
  if (mode == 2) {
    float g = gain[head] * QK_SCALE;  // fold 1/sqrt(d) into Q
    v0 *= g;
    v1 *= g;
  }
  short* dp = dst + ((size_t)(b * n_heads + head) * S_LEN + s) * HD;
  dp[lane] = f2h(v0);
  dp[lane + 64] = f2h(v1);
}

// ---------------------------------------------------------------------------
// Tiled transpose: vraw[token][512] -> vT[b][kv][dim128][seq2048].
// ---------------------------------------------------------------------------
__global__ __launch_bounds__(256) void v_transpose(const short* __restrict__ src,
                                                   short* __restrict__ dst) {
  __shared__ __align__(16) short t[64][72];
  const int tid = threadIdx.x;
  const int s0 = blockIdx.x * 64;
  const int d0 = blockIdx.y * 64;
#pragma unroll
  for (int i = 0; i < 2; i++) {
    int r = (tid >> 3) + i * 32;
    int c = (tid & 7) * 8;
    *reinterpret_cast<int4*>(&t[r][c]) =
        *reinterpret_cast<const int4*>(src + (size_t)(s0 + r) * 512 + d0 + c);
  }
  __syncthreads();
  const int b = s0 >> 11;
  const int sbase = s0 & (S_LEN - 1);
#pragma unroll
  for (int i = 0; i < 2; i++) {
    int dr = (tid >> 3) + i * 32;
    int sc8 = (tid & 7) * 8;
    int d = d0 + dr;
    int kv = d >> 7, dw = d & 127;
    short4 lo, hi;
    lo.x = t[sc8 + 0][dr]; lo.y = t[sc8 + 1][dr];
    lo.z = t[sc8 + 2][dr]; lo.w = t[sc8 + 3][dr];
    hi.x = t[sc8 + 4][dr]; hi.y = t[sc8 + 5][dr];
    hi.z = t[sc8 + 6][dr]; hi.w = t[sc8 + 7][dr];
    short* dp = dst + (((size_t)(b * NKV + kv) * HD + dw) * S_LEN) + sbase + sc8;
    *reinterpret_cast<short4*>(dp) = lo;
    *reinterpret_cast<short4*>(dp + 4) = hi;
  }
}

// ---------------------------------------------------------------------------
// Flash-style causal attention, R14 = R13 body + T13 defer-max (THR=8).
// Block = 4 waves; wave = 16 queries; pair-in-block over BQ=64 sub-blocks
// (512 uniform blocks, 2/CU, lb(256,2)). In-loop int4 staging (no register
// prefetch — R12 proved it spills). XCD stream swizzle: strm=D&7 -> (b,kvh).
// ---------------------------------------------------------------------------
__global__ __launch_bounds__(256, 2) void attn_fwd(const short* __restrict__ qb,
                                                   const short* __restrict__ kb,
                                                   const short* __restrict__ vT,
                                                   short* __restrict__ out) {
  __shared__ __align__(16) short k_lds[64][136];
  __shared__ __align__(16) short vt_lds[144][72];
  __shared__ __align__(16) short p_lds[4][16][72];

  const int tid = threadIdx.x, wave = tid >> 6, lane = tid & 63;
  const int quad = lane >> 4, l16 = lane & 15;
  const int D = blockIdx.x;
  const int strm = D & 7;      // KV stream -> XCD (round-robin assumption)
  const int t = D >> 3;        // 0..63
  const int pj = t >> 2;       // 0..15
  const int b = strm >> 2;     // 0..1
  const int kvh = strm & 3;    // 0..3
  const int h = kvh * 4 + (t & 3);

  const short* kptr = kb + ((size_t)(b * NKV + kvh) * S_LEN) * HD;
  const short* vtp  = vT + ((size_t)(b * NKV + kvh) * HD) * S_LEN;

  const int kr = (tid >> 4), kc = (tid & 15) * 8;
  const int vr = (tid >> 3), vc = (tid & 7) * 8;

  // ones-column tile (rows 128..143) for the rowsum-via-MFMA trick
  {
    int r = 128 + (tid >> 4);
    int c = (tid & 15) * 4;
    short val = (r == 128) ? (short)0x3C00 : (short)0;
    short4 v4 = {val, val, val, val};
    *reinterpret_cast<short4*>(&vt_lds[r][c]) = v4;
  }

  for (int pass = 0; pass < 2; pass++) {
    const int qsub = pass ? (31 - pj) : pj;
    const int q0 = qsub * 64 + wave * 16;
    const short* qptr = qb + ((size_t)(b * NH + h) * S_LEN + q0) * HD;

    f16x8 qf[4];
#pragma unroll
    for (int st = 0; st < 4; st++)
      qf[st] = *reinterpret_cast<const f16x8*>(
          qptr + (size_t)l16 * HD + st * 32 + quad * 8);

    f32x4 o[9];
#pragma unroll
    for (int i = 0; i < 9; i++) o[i] = f32x4{0.f, 0.f, 0.f, 0.f};
    float m_i[4] = {NEG_SENT, NEG_SENT, NEG_SENT, NEG_SENT};

    const int ktiles = qsub + 1;
    for (int kt = 0; kt < ktiles; kt++) {
      const int kbase = kt * 64;
      __syncthreads();  // prior tile's reads done before overwrite
#pragma unroll
      for (int i = 0; i < 4; i++)
        *reinterpret_cast<int4*>(&k_lds[kr + i * 16][kc]) =
            *reinterpret_cast<const int4*>(kptr + (size_t)(kbase + kr + i * 16) * HD + kc);
#pragma unroll
      for (int i = 0; i < 4; i++)
        *reinterpret_cast<int4*>(&vt_lds[vr + i * 32][vc]) =
            *reinterpret_cast<const int4*>(vtp + (size_t)(vr + i * 32) * S_LEN + kbase + vc);
      __syncthreads();  // staging visible (also covers ones-init on iter 0)

      f32x4 sc[4];
#pragma unroll
      for (int ct = 0; ct < 4; ct++) sc[ct] = f32x4{0.f, 0.f, 0.f, 0.f};
#pragma unroll
      for (int ct = 0; ct < 4; ct++) {
#pragma unroll
        for (int st = 0; st < 4; st++) {
          f16x8 kf = *reinterpret_cast<const f16x8*>(&k_lds[ct * 16 + l16][st * 32 + quad * 8]);
          sc[ct] = __builtin_amdgcn_mfma_f32_16x16x32_f16(qf[st], kf, sc[ct], 0, 0, 0);
        }
      }

      if (kbase + 63 > q0) {
#pragma unroll
        for (int ct = 0; ct < 4; ct++)
#pragma unroll
          for (int r = 0; r < 4; r++) {
            int qrow = q0 + quad * 4 + r;
            int col = kbase + ct * 16 + l16;
            sc[ct][r] = (col <= qrow) ? sc[ct][r] : NEG_SENT;
          }
      }

      float cand[4];
#pragma unroll
      for (int r = 0; r < 4; r++)
        cand[r] = fmaxf(fmaxf(sc[0][r], sc[1][r]), fmaxf(sc[2][r], sc[3][r]));
#pragma unroll
      for (int off = 1; off < 16; off <<= 1)
#pragma unroll
        for (int r = 0; r < 4; r++)
          cand[r] = fmaxf(cand[r], __shfl_xor(cand[r], off, 64));

      // T13 defer-max: only rescale when a row's max grew by > THR.
      // P is then bounded by exp(THR)=e^8~2981 (fp16-safe; f32 accum).
      bool ch = (cand[0] > m_i[0] + RESCALE_THR) | (cand[1] > m_i[1] + RESCALE_THR) |
                (cand[2] > m_i[2] + RESCALE_THR) | (cand[3] > m_i[3] + RESCALE_THR);
      if (__any(ch)) {
        float alpha[4];
#pragma unroll
        for (int r = 0; r < 4; r++) {
          float mn = fmaxf(m_i[r], cand[r]);
          alpha[r] = __expf(m_i[r] - mn);
          m_i[r] = mn;
        }
#pragma unroll
        for (int nt = 0; nt < 9; nt++)
#pragma unroll
          for (int r = 0; r < 4; r++) o[nt][r] *= alpha[r];
      }

#pragma unroll
      for (int ct = 0; ct < 4; ct++)
#pragma unroll
        for (int r = 0; r < 4; r++) {
          float p = __expf(sc[ct][r] - m_i[r]);
          p_lds[wave][quad * 4 + r][ct * 16 + l16] = f2h(p);
        }

      f16x8 pf0 = *reinterpret_cast<const f16x8*>(&p_lds[wave][l16][quad * 8]);
      f16x8 pf1 = *reinterpret_cast<const f16x8*>(&p_lds[wave][l16][32 + quad * 8]);
#pragma unroll
      for (int nt = 0; nt < 9; nt++) {
        f16x8 vf0 = *reinterpret_cast<const f16x8*>(&vt_lds[nt * 16 + l16][quad * 8]);
        f16x8 vf1 = *reinterpret_cast<const f16x8*>(&vt_lds[nt * 16 + l16][32 + quad * 8]);
        o[nt] = __builtin_amdgcn_mfma_f32_16x16x32_f16(pf0, vf0, o[nt], 0, 0, 0);
        o[nt] = __builtin_amdgcn_mfma_f32_16x16x32_f16(pf1, vf1, o[nt], 0, 0, 0);
      }
    }

    float inv_l[4];
#pragma unroll
    for (int r = 0; r < 4; r++) {
      float l = __shfl(o[8][r], lane & 48, 64);
      inv_l[r] = 1.0f / fmaxf(l, 1e-20f);
    }
#pragma unroll
    for (int nt = 0; nt < 8; nt++)
#pragma unroll
      for (int r = 0; r < 4; r++) {
        int srow = q0 + quad * 4 + r;
        int dcol = nt * 16 + l16;
        out[((size_t)(b * S_LEN + srow)) * DMODEL + h * HD + dcol] =
            f2h(o[nt][r] * inv_l[r]);
      }
  }
}

extern "C" void kernel_launch(void* const* d_in, const int* in_sizes, int n_in,
                              void* d_out, int out_size, void* d_ws, size_t ws_size,
                              hipStream_t stream) {
  const float* x      = (const float*)d_in[0];
  const float* q_w    = (const float*)d_in[1];
  const float* k_w    = (const float*)d_in[2];
  const float* v_w    = (const float*)d_in[3];
  const float* out_w  = (const float*)d_in[4];
  const float* q_gain = (const float*)d_in[5];
  float* out = (float*)d_out;

  const int BS = 2 * S_LEN;  // 4096 tokens
  short* xb   = (short*)d_ws;                    // 8M  (16MB)
  short* wqb  = xb   + (size_t)8 * 1024 * 1024;  // 4M
  short* wkb  = wqb  + (size_t)4 * 1024 * 1024;  // 1M
  short* wvb  = wkb  + (size_t)1 * 1024 * 1024;  // 1M
  short* wob  = wvb  + (size_t)1 * 1024 * 1024;  // 4M
  short* qraw = wob  + (size_t)4 * 1024 * 1024;  // 8M
  short* kraw = qraw + (size_t)8 * 1024 * 1024;  // 2M
  short* vraw = kraw + (size_t)2 * 1024 * 1024;  // 2M (token-major V)
  short* qbuf = vraw + (size_t)2 * 1024 * 1024;  // 8M
  short* kbuf = qbuf + (size_t)8 * 1024 * 1024;  // 2M
  short* vT   = kbuf + (size_t)2 * 1024 * 1024;  // 2M ([b][kv][dim][seq])
  short* attn = qraw;                            // alias

  dim3 blk(256);
  // one fused convert launch: 4718592 float4 / 256 = 18432 blocks
  f32_to_f16_all<<<18432, blk, 0, stream>>>(x, q_w, k_w, v_w, out_w,
                                            xb, wqb, wkb, wvb, wob);

  // Q/K/V projections in one 768-block launch
  gemm_qkv<<<dim3(32, 24), blk, 0, stream>>>(xb, wqb, wkb, wvb,
                                             qraw, kraw, vraw, 2048);

  postproc<<<dim3((BS * NH) / 4), blk, 0, stream>>>(qraw, qbuf, q_gain, NH, 2);
  postproc<<<dim3((BS * NKV) / 4), blk, 0, stream>>>(kraw, kbuf, q_gain, NKV, 1);
  v_transpose<<<dim3(BS / 64, 8), blk, 0, stream>>>(vraw, vT);

  attn_fwd<<<dim3(512), blk, 0, stream>>>(qbuf, kbuf, vT, attn);

  gemm_bt<true><<<dim3(32, 16), blk, 0, stream>>>(attn, wob, out, 2048, 2048);
}

// Round 7
// 368.340 us; speedup vs baseline: 1.1863x; 1.1863x over previous
//
#include <hip/hip_runtime.h>
#include <cmath>

// CausalSelfAttention fused pipeline, MI355X/gfx950.
// R16 = R15 resubmitted (round 6 bench was an infra failure, no signal).
// GEMM core = counted-vmcnt pipeline with TWO LDS slots (64KB ->
// 2 blocks/CU). R14's 3-slot/96KB variant proved the pipeline mechanism
// (per-block MFMA rate 3x R13's) but collapsed residency to 1 block/CU.
// vmcnt ledger: prologue stage t0 (8); iter t: stage t+1 (16) -> vmcnt(8)
// -> s_barrier -> compute slot t&1 -> lgkmcnt(0)+sched_barrier -> s_barrier.
// attn: R13 body + T13 defer-max (passed R14, absmax unchanged).

#define S_LEN 2048
#define DMODEL 2048
#define NH 16
#define NKV 4
#define HD 128

#define NEG_SENT -1.0e30f
#define QK_SCALE 0.08838834764831845f  // 1/sqrt(128), folded into Q
#define RESCALE_THR 8.0f               // T13 defer-max threshold

typedef _Float16 f16x8 __attribute__((ext_vector_type(8)));
typedef float f32x4 __attribute__((ext_vector_type(4)));

static __device__ __forceinline__ short f2h(float f) {
  _Float16 h = (_Float16)f;
  return *(short*)&h;
}
static __device__ __forceinline__ float h2f(short s) {
  _Float16 h = *(_Float16*)&s;
  return (float)h;
}

// async global->LDS, 16B per lane; lds dst = wave-uniform base + lane*16.
static __device__ __forceinline__ void stage16(const short* g, short* ldsbase) {
  __builtin_amdgcn_global_load_lds(
      (const __attribute__((address_space(1))) void*)g,
      (__attribute__((address_space(3))) void*)ldsbase, 16, 0, 0);
}

// ---------------------------------------------------------------------------
// Fused fp32 -> fp16 convert for all five tensors in one launch.
// Segment sizes in float4 units (all multiples of 256 -> block-uniform
// branch): x 2097152 | q_w 1048576 | k_w 262144 | v_w 262144 | out_w 1048576
// ---------------------------------------------------------------------------
__global__ __launch_bounds__(256) void f32_to_f16_all(
    const float* __restrict__ s0, const float* __restrict__ s1,
    const float* __restrict__ s2, const float* __restrict__ s3,
    const float* __restrict__ s4, short* __restrict__ d0,
    short* __restrict__ d1, short* __restrict__ d2, short* __restrict__ d3,
    short* __restrict__ d4) {
  int u = blockIdx.x * 256 + threadIdx.x;  // float4 index
  const float* src;
  short* dst;
  int off;
  if (u < 2097152) {
    src = s0; dst = d0; off = u;
  } else if (u < 3145728) {
    src = s1; dst = d1; off = u - 2097152;
  } else if (u < 3407872) {
    src = s2; dst = d2; off = u - 3145728;
  } else if (u < 3670016) {
    src = s3; dst = d3; off = u - 3407872;
  } else {
    src = s4; dst = d4; off = u - 3670016;
  }
  float4 v = *reinterpret_cast<const float4*>(src + (size_t)off * 4);
  short4 o;
  o.x = f2h(v.x); o.y = f2h(v.y); o.z = f2h(v.z); o.w = f2h(v.w);
  *reinterpret_cast<short4*>(dst + (size_t)off * 4) = o;
}

// ---------------------------------------------------------------------------
// GEMM core, R15/R16: C[M,N] = A[M,K] @ W[N,K]^T, fp16 in, fp32 accum.
// 128x128 tile, BK=64, 2-slot LDS ring (64KB -> 2 blocks/CU), counted-vmcnt
// pipeline. Staging addresses identical to the verified core: wave w stages
// rows {w*8 + i*32 + lane/8}, cols (lane&7)*8 into unpadded [128][64] slots.
// vmcnt ledger (8 global_load_lds per wave per tile):
//   prologue: stage t0          (8 outstanding)
//   iter t:   stage t+1         (16) -> vmcnt(8) retires tile t's loads
//   t=NT-1:   no stage          -> vmcnt(0)
// Raw s_barrier (no implicit vmcnt(0) drain); lgkmcnt(0)+sched_barrier(0)
// then s_barrier at tile end so the slot is safe for re-staging at t+2.
// Correctness of this sync structure was verified in R14 (absmax identical).
// ---------------------------------------------------------------------------
template <bool F32OUT>
static __device__ __forceinline__ void gemm_core(const short* __restrict__ A,
                                                 const short* __restrict__ W,
                                                 void* __restrict__ Cv,
                                                 int N, int K, int bm, int bn) {
  __shared__ __align__(16) short As[2][128][64];
  __shared__ __align__(16) short Ws[2][128][64];
  const int tid = threadIdx.x;
  const int wave = tid >> 6, lane = tid & 63;
  const int quad = lane >> 4, l16 = lane & 15;
  const int wm = (wave >> 1) * 64, wn = (wave & 1) * 64;

  f32x4 acc[4][4];
#pragma unroll
  for (int i = 0; i < 4; i++)
#pragma unroll
    for (int j = 0; j < 4; j++) acc[i][j] = f32x4{0.f, 0.f, 0.f, 0.f};

  const int srow = wave * 8 + (lane >> 3);  // staging row (this lane)
  const int scol = (lane & 7) * 8;          // staging col

  const int NT = K >> 6;  // K-tiles (K=2048 -> 32; always >= 2 here)

  auto stage_tile = [&](int t, int s) {
    const int k0 = t * 64;
#pragma unroll
    for (int i = 0; i < 4; i++) {
      stage16(A + (size_t)(bm + srow + i * 32) * K + k0 + scol,
              &As[s][wave * 8 + i * 32][0]);
      stage16(W + (size_t)(bn + srow + i * 32) * K + k0 + scol,
              &Ws[s][wave * 8 + i * 32][0]);
    }
  };

  stage_tile(0, 0);

  for (int t = 0; t < NT; t++) {
    const int s = t & 1;
    if (t + 1 < NT) {
      stage_tile(t + 1, s ^ 1);  // slot s^1 was drained at end of iter t-1
      asm volatile("s_waitcnt vmcnt(8)" ::: "memory");
    } else {
      asm volatile("s_waitcnt vmcnt(0)" ::: "memory");
    }
    __builtin_amdgcn_s_barrier();  // all waves' tile-t loads landed

#pragma unroll
    for (int kk = 0; kk < 64; kk += 32) {
      f16x8 af[4], bfr[4];
#pragma unroll
      for (int mi = 0; mi < 4; mi++)
        af[mi] = *reinterpret_cast<const f16x8*>(&As[s][wm + mi * 16 + l16][kk + quad * 8]);
#pragma unroll
      for (int ni = 0; ni < 4; ni++)
        bfr[ni] = *reinterpret_cast<const f16x8*>(&Ws[s][wn + ni * 16 + l16][kk + quad * 8]);
#pragma unroll
      for (int mi = 0; mi < 4; mi++)
#pragma unroll
        for (int ni = 0; ni < 4; ni++)
          acc[mi][ni] = __builtin_amdgcn_mfma_f32_16x16x32_f16(af[mi], bfr[ni], acc[mi][ni], 0, 0, 0);
    }

    if (t + 1 < NT) {
      // drain this tile's ds_reads before slot s can be re-staged (iter t+1)
      asm volatile("s_waitcnt lgkmcnt(0)" ::: "memory");
      __builtin_amdgcn_sched_barrier(0);
      __builtin_amdgcn_s_barrier();
    }
  }

  // C/D layout: row = quad*4 + r, col = l16
#pragma unroll
  for (int mi = 0; mi < 4; mi++)
#pragma unroll
    for (int ni = 0; ni < 4; ni++) {
      int gr = bm + wm + mi * 16 + quad * 4;
      int gc = bn + wn + ni * 16 + l16;
#pragma unroll
      for (int r = 0; r < 4; r++) {
        if (F32OUT)
          ((float*)Cv)[(size_t)(gr + r) * N + gc] = acc[mi][ni][r];
        else
          ((short*)Cv)[(size_t)(gr + r) * N + gc] = f2h(acc[mi][ni][r]);
      }
    }
}

template <bool F32OUT>
__global__ __launch_bounds__(256) void gemm_bt(const short* __restrict__ A,
                                               const short* __restrict__ W,
                                               void* __restrict__ Cv,
                                               int N, int K) {
  gemm_core<F32OUT>(A, W, Cv, N, K, blockIdx.x * 128, blockIdx.y * 128);
}

// Q, K, V projections in ONE launch. Grid (32, 24): y<16 -> Q (N=2048),
// y in [16,20) -> K, y in [20,24) -> V (N=512). Block-uniform branch.
__global__ __launch_bounds__(256) void gemm_qkv(const short* __restrict__ A,
                                                const short* __restrict__ Wq,
                                                const short* __restrict__ Wk,
                                                const short* __restrict__ Wv,
                                                short* __restrict__ Cq,
                                                short* __restrict__ Ck,
                                                short* __restrict__ Cvp,
                                                int K) {
  const int y = blockIdx.y;
  const short* W;
  short* C;
  int N, bn;
  if (y < 16) {
    W = Wq; C = Cq; N = 2048; bn = y * 128;
  } else if (y < 20) {
    W = Wk; C = Ck; N = 512; bn = (y - 16) * 128;
  } else {
    W = Wv; C = Cvp; N = 512; bn = (y - 20) * 128;
  }
  gemm_core<false>(A, W, (void*)C, N, K, blockIdx.x * 128, bn);
}

// ---------------------------------------------------------------------------
// Per-(token,head) RMSNorm + partial RoPE + optional gain, relayout to
// [b][head][s][128]. mode: 1=norm+rope(k), 2=norm+rope+gain*qk_scale(q).
// ---------------------------------------------------------------------------
__global__ __launch_bounds__(256) void postproc(const short* __restrict__ src,
                                                short* __restrict__ dst,
                                                const float* __restrict__ gain,
                                                int n_heads, int mode) {
  int gw = blockIdx.x * 4 + (threadIdx.x >> 6);
  int lane = threadIdx.x & 63;
  int head = gw % n_heads;
  int token = gw / n_heads;
  int s = token & (S_LEN - 1);
  int b = token >> 11;
  const short* sp = src + (size_t)token * (n_heads * HD) + head * HD;
  float v0 = h2f(sp[lane]);
  float v1 = h2f(sp[lane + 64]);
  float ss = v0 * v0 + v1 * v1;
#pragma unroll
  for (int off = 1; off < 64; off <<= 1) ss += __shfl_xor(ss, off, 64);
  float sc = rsqrtf(ss * (1.0f / 128.0f) + 1.1920929e-07f);
  v0 *= sc;
  v1 *= sc;
  int i = lane & 31;
  float inv = powf(10000.0f, -((float)(2 * i) * (1.0f / 64.0f)));
  float f = (float)s * inv;
  float cs, sn;
  sincosf(f, &sn, &cs);
  float partner = __shfl_xor(v0, 32, 64);
  v0 = (lane < 32) ? (v0 * cs + partner * sn) : (v0 * cs - partner * sn);
  if (mode == 2) {
    float g = gain[head] * QK_SCALE;  // fold 1/sqrt(d) into Q
    v0 *= g;
    v1 *= g;
  }
  short* dp = dst + ((size_t)(b * n_heads + head) * S_LEN + s) * HD;
  dp[lane] = f2h(v0);
  dp[lane + 64] = f2h(v1);
}

// ---------------------------------------------------------------------------
// Tiled transpose: vraw[token][512] -> vT[b][kv][dim128][seq2048].
// ---------------------------------------------------------------------------
__global__ __launch_bounds__(256) void v_transpose(const short* __restrict__ src,
                                                   short* __restrict__ dst) {
  __shared__ __align__(16) short t[64][72];
  const int tid = threadIdx.x;
  const int s0 = blockIdx.x * 64;
  const int d0 = blockIdx.y * 64;
#pragma unroll
  for (int i = 0; i < 2; i++) {
    int r = (tid >> 3) + i * 32;
    int c = (tid & 7) * 8;
    *reinterpret_cast<int4*>(&t[r][c]) =
        *reinterpret_cast<const int4*>(src + (size_t)(s0 + r) * 512 + d0 + c);
  }
  __syncthreads();
  const int b = s0 >> 11;
  const int sbase = s0 & (S_LEN - 1);
#pragma unroll
  for (int i = 0; i < 2; i++) {
    int dr = (tid >> 3) + i * 32;
    int sc8 = (tid & 7) * 8;
    int d = d0 + dr;
    int kv = d >> 7, dw = d & 127;
    short4 lo, hi;
    lo.x = t[sc8 + 0][dr]; lo.y = t[sc8 + 1][dr];
    lo.z = t[sc8 + 2][dr]; lo.w = t[sc8 + 3][dr];
    hi.x = t[sc8 + 4][dr]; hi.y = t[sc8 + 5][dr];
    hi.z = t[sc8 + 6][dr]; hi.w = t[sc8 + 7][dr];
    short* dp = dst + (((size_t)(b * NKV + kv) * HD + dw) * S_LEN) + sbase + sc8;
    *reinterpret_cast<short4*>(dp) = lo;
    *reinterpret_cast<short4*>(dp + 4) = hi;
  }
}

// ---------------------------------------------------------------------------
// Flash-style causal attention, = R13 body + T13 defer-max (THR=8).
// Block = 4 waves; wave = 16 queries; pair-in-block over BQ=64 sub-blocks
// (512 uniform blocks, 2/CU, lb(256,2)). In-loop int4 staging (no register
// prefetch — R12 proved it spills). XCD stream swizzle: strm=D&7 -> (b,kvh).
// ---------------------------------------------------------------------------
__global__ __launch_bounds__(256, 2) void attn_fwd(const short* __restrict__ qb,
                                                   const short* __restrict__ kb,
                                                   const short* __restrict__ vT,
                                                   short* __restrict__ out) {
  __shared__ __align__(16) short k_lds[64][136];
  __shared__ __align__(16) short vt_lds[144][72];
  __shared__ __align__(16) short p_lds[4][16][72];

  const int tid = threadIdx.x, wave = tid >> 6, lane = tid & 63;
  const int quad = lane >> 4, l16 = lane & 15;
  const int D = blockIdx.x;
  const int strm = D & 7;      // KV stream -> XCD (round-robin assumption)
  const int t = D >> 3;        // 0..63
  const int pj = t >> 2;       // 0..15
  const int b = strm >> 2;     // 0..1
  const int kvh = strm & 3;    // 0..3
  const int h = kvh * 4 + (t & 3);

  const short* kptr = kb + ((size_t)(b * NKV + kvh) * S_LEN) * HD;
  const short* vtp  = vT + ((size_t)(b * NKV + kvh) * HD) * S_LEN;

  const int kr = (tid >> 4), kc = (tid & 15) * 8;
  const int vr = (tid >> 3), vc = (tid & 7) * 8;

  // ones-column tile (rows 128..143) for the rowsum-via-MFMA trick
  {
    int r = 128 + (tid >> 4);
    int c = (tid & 15) * 4;
    short val = (r == 128) ? (short)0x3C00 : (short)0;
    short4 v4 = {val, val, val, val};
    *reinterpret_cast<short4*>(&vt_lds[r][c]) = v4;
  }

  for (int pass = 0; pass < 2; pass++) {
    const int qsub = pass ? (31 - pj) : pj;
    const int q0 = qsub * 64 + wave * 16;
    const short* qptr = qb + ((size_t)(b * NH + h) * S_LEN + q0) * HD;

    f16x8 qf[4];
#pragma unroll
    for (int st = 0; st < 4; st++)
      qf[st] = *reinterpret_cast<const f16x8*>(
          qptr + (size_t)l16 * HD + st * 32 + quad * 8);

    f32x4 o[9];
#pragma unroll
    for (int i = 0; i < 9; i++) o[i] = f32x4{0.f, 0.f, 0.f, 0.f};
    float m_i[4] = {NEG_SENT, NEG_SENT, NEG_SENT, NEG_SENT};

    const int ktiles = qsub + 1;
    for (int kt = 0; kt < ktiles; kt++) {
      const int kbase = kt * 64;
      __syncthreads();  // prior tile's reads done before overwrite
#pragma unroll
      for (int i = 0; i < 4; i++)
        *reinterpret_cast<int4*>(&k_lds[kr + i * 16][kc]) =
            *reinterpret_cast<const int4*>(kptr + (size_t)(kbase + kr + i * 16) * HD + kc);
#pragma unroll
      for (int i = 0; i < 4; i++)
        *reinterpret_cast<int4*>(&vt_lds[vr + i * 32][vc]) =
            *reinterpret_cast<const int4*>(vtp + (size_t)(vr + i * 32) * S_LEN + kbase + vc);
      __syncthreads();  // staging visible (also covers ones-init on iter 0)

      f32x4 sc[4];
#pragma unroll
      for (int ct = 0; ct < 4; ct++) sc[ct] = f32x4{0.f, 0.f, 0.f, 0.f};
#pragma unroll
      for (int ct = 0; ct < 4; ct++) {
#pragma unroll
        for (int st = 0; st < 4; st++) {
          f16x8 kf = *reinterpret_cast<const f16x8*>(&k_lds[ct * 16 + l16][st * 32 + quad * 8]);
          sc[ct] = __builtin_amdgcn_mfma_f32_16x16x32_f16(qf[st], kf, sc[ct], 0, 0, 0);
        }
      }

      if (kbase + 63 > q0) {
#pragma unroll
        for (int ct = 0; ct < 4; ct++)
#pragma unroll
          for (int r = 0; r < 4; r++) {
            int qrow = q0 + quad * 4 + r;
            int col = kbase + ct * 16 + l16;
            sc[ct][r] = (col <= qrow) ? sc[ct][r] : NEG_SENT;
          }
      }

      float cand[4];
#pragma unroll
      for (int r = 0; r < 4; r++)
        cand[r] = fmaxf(fmaxf(sc[0][r], sc[1][r]), fmaxf(sc[2][r], sc[3][r]));
#pragma unroll
      for (int off = 1; off < 16; off <<= 1)
#pragma unroll
        for (int r = 0; r < 4; r++)
          cand[r] = fmaxf(cand[r], __shfl_xor(cand[r], off, 64));

      // T13 defer-max: only rescale when a row's max grew by > THR.
      // P is then bounded by exp(THR)=e^8~2981 (fp16-safe; f32 accum).
      bool ch = (cand[0] > m_i[0] + RESCALE_THR) | (cand[1] > m_i[1] + RESCALE_THR) |
                (cand[2] > m_i[2] + RESCALE_THR) | (cand[3] > m_i[3] + RESCALE_THR);
      if (__any(ch)) {
        float alpha[4];
#pragma unroll
        for (int r = 0; r < 4; r++) {
          float mn = fmaxf(m_i[r], cand[r]);
          alpha[r] = __expf(m_i[r] - mn);
          m_i[r] = mn;
        }
#pragma unroll
        for (int nt = 0; nt < 9; nt++)
#pragma unroll
          for (int r = 0; r < 4; r++) o[nt][r] *= alpha[r];
      }

#pragma unroll
      for (int ct = 0; ct < 4; ct++)
#pragma unroll
        for (int r = 0; r < 4; r++) {
          float p = __expf(sc[ct][r] - m_i[r]);
          p_lds[wave][quad * 4 + r][ct * 16 + l16] = f2h(p);
        }

      f16x8 pf0 = *reinterpret_cast<const f16x8*>(&p_lds[wave][l16][quad * 8]);
      f16x8 pf1 = *reinterpret_cast<const f16x8*>(&p_lds[wave][l16][32 + quad * 8]);
#pragma unroll
      for (int nt = 0; nt < 9; nt++) {
        f16x8 vf0 = *reinterpret_cast<const f16x8*>(&vt_lds[nt * 16 + l16][quad * 8]);
        f16x8 vf1 = *reinterpret_cast<const f16x8*>(&vt_lds[nt * 16 + l16][32 + quad * 8]);
        o[nt] = __builtin_amdgcn_mfma_f32_16x16x32_f16(pf0, vf0, o[nt], 0, 0, 0);
        o[nt] = __builtin_amdgcn_mfma_f32_16x16x32_f16(pf1, vf1, o[nt], 0, 0, 0);
      }
    }

    float inv_l[4];
#pragma unroll
    for (int r = 0; r < 4; r++) {
      float l = __shfl(o[8][r], lane & 48, 64);
      inv_l[r] = 1.0f / fmaxf(l, 1e-20f);
    }
#pragma unroll
    for (int nt = 0; nt < 8; nt++)
#pragma unroll
      for (int r = 0; r < 4; r++) {
        int srow = q0 + quad * 4 + r;
        int dcol = nt * 16 + l16;
        out[((size_t)(b * S_LEN + srow)) * DMODEL + h * HD + dcol] =
            f2h(o[nt][r] * inv_l[r]);
      }
  }
}

extern "C" void kernel_launch(void* const* d_in, const int* in_sizes, int n_in,
                              void* d_out, int out_size, void* d_ws, size_t ws_size,
                              hipStream_t stream) {
  const float* x      = (const float*)d_in[0];
  const float* q_w    = (const float*)d_in[1];
  const float* k_w    = (const float*)d_in[2];
  const float* v_w    = (const float*)d_in[3];
  const float* out_w  = (const float*)d_in[4];
  const float* q_gain = (const float*)d_in[5];
  float* out = (float*)d_out;

  const int BS = 2 * S_LEN;  // 4096 tokens
  short* xb   = (short*)d_ws;                    // 8M  (16MB)
  short* wqb  = xb   + (size_t)8 * 1024 * 1024;  // 4M
  short* wkb  = wqb  + (size_t)4 * 1024 * 1024;  // 1M
  short* wvb  = wkb  + (size_t)1 * 1024 * 1024;  // 1M
  short* wob  = wvb  + (size_t)1 * 1024 * 1024;  // 4M
  short* qraw = wob  + (size_t)4 * 1024 * 1024;  // 8M
  short* kraw = qraw + (size_t)8 * 1024 * 1024;  // 2M
  short* vraw = kraw + (size_t)2 * 1024 * 1024;  // 2M (token-major V)
  short* qbuf = vraw + (size_t)2 * 1024 * 1024;  // 8M
  short* kbuf = qbuf + (size_t)8 * 1024 * 1024;  // 2M
  short* vT   = kbuf + (size_t)2 * 1024 * 1024;  // 2M ([b][kv][dim][seq])
  short* attn = qraw;                            // alias

  dim3 blk(256);
  // one fused convert launch: 4718592 float4 / 256 = 18432 blocks
  f32_to_f16_all<<<18432, blk, 0, stream>>>(x, q_w, k_w, v_w, out_w,
                                            xb, wqb, wkb, wvb, wob);

  // Q/K/V projections in one 768-block launch
  gemm_qkv<<<dim3(32, 24), blk, 0, stream>>>(xb, wqb, wkb, wvb,
                                             qraw, kraw, vraw, 2048);

  postproc<<<dim3((BS * NH) / 4), blk, 0, stream>>>(qraw, qbuf, q_gain, NH, 2);
  postproc<<<dim3((BS * NKV) / 4), blk, 0, stream>>>(kraw, kbuf, q_gain, NKV, 1);
  v_transpose<<<dim3(BS / 64, 8), blk, 0, stream>>>(vraw, vT);

  attn_fwd<<<dim3(512), blk, 0, stream>>>(qbuf, kbuf, vT, attn);

  gemm_bt<true><<<dim3(32, 16), blk, 0, stream>>>(attn, wob, out, 2048, 2048);
}

// Round 8
// 348.184 us; speedup vs baseline: 1.2550x; 1.0579x over previous
//
#include <hip/hip_runtime.h>
#include <cmath>

// CausalSelfAttention fused pipeline, MI355X/gfx950.
// R17: postproc (RMSNorm+RoPE+gain) and v_transpose FUSED into gemm_qkv's
// epilogue. The 128-wide N-tile of gemm_qkv is exactly one head, and the
// 128-row M-tile is 128 consecutive tokens, so each block's C-tile holds
// complete (token,head) rows: norm over head-dim = norm over the N-tile.
// Staging LDS (dead after K-loop) is reused as f16 ep[128][132]; epilogue
// math copied verbatim from the verified postproc/v_transpose kernels.
// K-loop = R15/R16 verified counted-vmcnt 2-slot pipeline (unchanged).
// attn = R13 body + T13 defer-max (unchanged). 4 launches total (was 7).

#define S_LEN 2048
#define DMODEL 2048
#define NH 16
#define NKV 4
#define HD 128

#define NEG_SENT -1.0e30f
#define QK_SCALE 0.08838834764831845f  // 1/sqrt(128), folded into Q
#define RESCALE_THR 8.0f               // T13 defer-max threshold

typedef _Float16 f16x8 __attribute__((ext_vector_type(8)));
typedef float f32x4 __attribute__((ext_vector_type(4)));

static __device__ __forceinline__ short f2h(float f) {
  _Float16 h = (_Float16)f;
  return *(short*)&h;
}
static __device__ __forceinline__ float h2f(short s) {
  _Float16 h = *(_Float16*)&s;
  return (float)h;
}

// async global->LDS, 16B per lane; lds dst = wave-uniform base + lane*16.
static __device__ __forceinline__ void stage16(const short* g, short* ldsbase) {
  __builtin_amdgcn_global_load_lds(
      (const __attribute__((address_space(1))) void*)g,
      (__attribute__((address_space(3))) void*)ldsbase, 16, 0, 0);
}

// ---------------------------------------------------------------------------
// Fused fp32 -> fp16 convert for all five tensors in one launch.
// Segment sizes in float4 units (all multiples of 256 -> block-uniform
// branch): x 2097152 | q_w 1048576 | k_w 262144 | v_w 262144 | out_w 1048576
// ---------------------------------------------------------------------------
__global__ __launch_bounds__(256) void f32_to_f16_all(
    const float* __restrict__ s0, const float* __restrict__ s1,
    const float* __restrict__ s2, const float* __restrict__ s3,
    const float* __restrict__ s4, short* __restrict__ d0,
    short* __restrict__ d1, short* __restrict__ d2, short* __restrict__ d3,
    short* __restrict__ d4) {
  int u = blockIdx.x * 256 + threadIdx.x;  // float4 index
  const float* src;
  short* dst;
  int off;
  if (u < 2097152) {
    src = s0; dst = d0; off = u;
  } else if (u < 3145728) {
    src = s1; dst = d1; off = u - 2097152;
  } else if (u < 3407872) {
    src = s2; dst = d2; off = u - 3145728;
  } else if (u < 3670016) {
    src = s3; dst = d3; off = u - 3407872;
  } else {
    src = s4; dst = d4; off = u - 3670016;
  }
  float4 v = *reinterpret_cast<const float4*>(src + (size_t)off * 4);
  short4 o;
  o.x = f2h(v.x); o.y = f2h(v.y); o.z = f2h(v.z); o.w = f2h(v.w);
  *reinterpret_cast<short4*>(dst + (size_t)off * 4) = o;
}

// ---------------------------------------------------------------------------
// GEMM core (for the out-projection): C[M,N] = A[M,K] @ W[N,K]^T.
// 128x128 tile, BK=64, 2-slot LDS ring (64KB -> 2 blocks/CU), counted-vmcnt
// pipeline (verified R14/R15/R16).
// ---------------------------------------------------------------------------
template <bool F32OUT>
static __device__ __forceinline__ void gemm_core(const short* __restrict__ A,
                                                 const short* __restrict__ W,
                                                 void* __restrict__ Cv,
                                                 int N, int K, int bm, int bn) {
  __shared__ __align__(16) short As[2][128][64];
  __shared__ __align__(16) short Ws[2][128][64];
  const int tid = threadIdx.x;
  const int wave = tid >> 6, lane = tid & 63;
  const int quad = lane >> 4, l16 = lane & 15;
  const int wm = (wave >> 1) * 64, wn = (wave & 1) * 64;

  f32x4 acc[4][4];
#pragma unroll
  for (int i = 0; i < 4; i++)
#pragma unroll
    for (int j = 0; j < 4; j++) acc[i][j] = f32x4{0.f, 0.f, 0.f, 0.f};

  const int srow = wave * 8 + (lane >> 3);
  const int scol = (lane & 7) * 8;
  const int NT = K >> 6;

  auto stage_tile = [&](int t, int s) {
    const int k0 = t * 64;
#pragma unroll
    for (int i = 0; i < 4; i++) {
      stage16(A + (size_t)(bm + srow + i * 32) * K + k0 + scol,
              &As[s][wave * 8 + i * 32][0]);
      stage16(W + (size_t)(bn + srow + i * 32) * K + k0 + scol,
              &Ws[s][wave * 8 + i * 32][0]);
    }
  };

  stage_tile(0, 0);

  for (int t = 0; t < NT; t++) {
    const int s = t & 1;
    if (t + 1 < NT) {
      stage_tile(t + 1, s ^ 1);
      asm volatile("s_waitcnt vmcnt(8)" ::: "memory");
    } else {
      asm volatile("s_waitcnt vmcnt(0)" ::: "memory");
    }
    __builtin_amdgcn_s_barrier();

#pragma unroll
    for (int kk = 0; kk < 64; kk += 32) {
      f16x8 af[4], bfr[4];
#pragma unroll
      for (int mi = 0; mi < 4; mi++)
        af[mi] = *reinterpret_cast<const f16x8*>(&As[s][wm + mi * 16 + l16][kk + quad * 8]);
#pragma unroll
      for (int ni = 0; ni < 4; ni++)
        bfr[ni] = *reinterpret_cast<const f16x8*>(&Ws[s][wn + ni * 16 + l16][kk + quad * 8]);
#pragma unroll
      for (int mi = 0; mi < 4; mi++)
#pragma unroll
        for (int ni = 0; ni < 4; ni++)
          acc[mi][ni] = __builtin_amdgcn_mfma_f32_16x16x32_f16(af[mi], bfr[ni], acc[mi][ni], 0, 0, 0);
    }

    if (t + 1 < NT) {
      asm volatile("s_waitcnt lgkmcnt(0)" ::: "memory");
      __builtin_amdgcn_sched_barrier(0);
      __builtin_amdgcn_s_barrier();
    }
  }

#pragma unroll
  for (int mi = 0; mi < 4; mi++)
#pragma unroll
    for (int ni = 0; ni < 4; ni++) {
      int gr = bm + wm + mi * 16 + quad * 4;
      int gc = bn + wn + ni * 16 + l16;
#pragma unroll
      for (int r = 0; r < 4; r++) {
        if (F32OUT)
          ((float*)Cv)[(size_t)(gr + r) * N + gc] = acc[mi][ni][r];
        else
          ((short*)Cv)[(size_t)(gr + r) * N + gc] = f2h(acc[mi][ni][r]);
      }
    }
}

template <bool F32OUT>
__global__ __launch_bounds__(256) void gemm_bt(const short* __restrict__ A,
                                               const short* __restrict__ W,
                                               void* __restrict__ Cv,
                                               int N, int K) {
  gemm_core<F32OUT>(A, W, Cv, N, K, blockIdx.x * 128, blockIdx.y * 128);
}

// ---------------------------------------------------------------------------
// Q/K/V projections + fused postproc/transpose epilogue. Grid (32, 24):
//   y<16: Q head y     -> RMSNorm+RoPE+gain -> qbuf[b][16][s][128]
//   16..19: K head y-16 -> RMSNorm+RoPE      -> kbuf[b][4][s][128]
//   20..23: V head y-20 -> transpose         -> vT[b][4][128][seq]
// K-loop identical to gemm_core (verified). LDS reused post-loop as
// f16 ep[128][132] (33.8KB <= 64KB staging footprint).
// ---------------------------------------------------------------------------
__global__ __launch_bounds__(256) void gemm_qkv(const short* __restrict__ A,
                                                const short* __restrict__ Wq,
                                                const short* __restrict__ Wk,
                                                const short* __restrict__ Wv,
                                                short* __restrict__ Cq,
                                                short* __restrict__ Ck,
                                                short* __restrict__ vT,
                                                const float* __restrict__ gain,
                                                int K) {
  __shared__ __align__(16) char smraw[65536];
  auto As = reinterpret_cast<short(*)[128][64]>(smraw);           // [2][128][64]
  auto Ws = reinterpret_cast<short(*)[128][64]>(smraw + 32768);   // [2][128][64]
  auto ep = reinterpret_cast<short(*)[132]>(smraw);               // [128][132]

  const int y = blockIdx.y;
  const short* W;
  int mode;  // 2=Q, 1=K, 0=V   (block-uniform)
  int bn;
  if (y < 16) {
    W = Wq; bn = y * 128; mode = 2;
  } else if (y < 20) {
    W = Wk; bn = (y - 16) * 128; mode = 1;
  } else {
    W = Wv; bn = (y - 20) * 128; mode = 0;
  }
  const int bm = blockIdx.x * 128;

  const int tid = threadIdx.x;
  const int wave = tid >> 6, lane = tid & 63;
  const int quad = lane >> 4, l16 = lane & 15;
  const int wm = (wave >> 1) * 64, wn = (wave & 1) * 64;

  f32x4 acc[4][4];
#pragma unroll
  for (int i = 0; i < 4; i++)
#pragma unroll
    for (int j = 0; j < 4; j++) acc[i][j] = f32x4{0.f, 0.f, 0.f, 0.f};

  const int srow = wave * 8 + (lane >> 3);
  const int scol = (lane & 7) * 8;
  const int NT = K >> 6;

  auto stage_tile = [&](int t, int s) {
    const int k0 = t * 64;
#pragma unroll
    for (int i = 0; i < 4; i++) {
      stage16(A + (size_t)(bm + srow + i * 32) * K + k0 + scol,
              &As[s][wave * 8 + i * 32][0]);
      stage16(W + (size_t)(bn + srow + i * 32) * K + k0 + scol,
              &Ws[s][wave * 8 + i * 32][0]);
    }
  };

  stage_tile(0, 0);

  for (int t = 0; t < NT; t++) {
    const int s = t & 1;
    if (t + 1 < NT) {
      stage_tile(t + 1, s ^ 1);
      asm volatile("s_waitcnt vmcnt(8)" ::: "memory");
    } else {
      asm volatile("s_waitcnt vmcnt(0)" ::: "memory");
    }
    __builtin_amdgcn_s_barrier();

#pragma unroll
    for (int kk = 0; kk < 64; kk += 32) {
      f16x8 af[4], bfr[4];
#pragma unroll
      for (int mi = 0; mi < 4; mi++)
        af[mi] = *reinterpret_cast<const f16x8*>(&As[s][wm + mi * 16 + l16][kk + quad * 8]);
#pragma unroll
      for (int ni = 0; ni < 4; ni++)
        bfr[ni] = *reinterpret_cast<const f16x8*>(&Ws[s][wn + ni * 16 + l16][kk + quad * 8]);
#pragma unroll
      for (int mi = 0; mi < 4; mi++)
#pragma unroll
        for (int ni = 0; ni < 4; ni++)
          acc[mi][ni] = __builtin_amdgcn_mfma_f32_16x16x32_f16(af[mi], bfr[ni], acc[mi][ni], 0, 0, 0);
    }

    if (t + 1 < NT) {
      asm volatile("s_waitcnt lgkmcnt(0)" ::: "memory");
      __builtin_amdgcn_sched_barrier(0);
      __builtin_amdgcn_s_barrier();
    }
  }

  // ---- fused epilogue ----
  __syncthreads();  // all waves done reading As/Ws before ep overwrite
#pragma unroll
  for (int mi = 0; mi < 4; mi++)
#pragma unroll
    for (int ni = 0; ni < 4; ni++) {
      const int er = wm + mi * 16 + quad * 4;
      const int ec = wn + ni * 16 + l16;
#pragma unroll
      for (int r = 0; r < 4; r++) ep[er + r][ec] = f2h(acc[mi][ni][r]);
    }
  __syncthreads();  // ep complete

  if (mode == 0) {
    // V: transpose ep[token][dim] -> vT[b][kv][dim][seq]
    const int d = tid >> 1;        // 0..127
    const int half = tid & 1;      // 0..1
    const int kvh2 = y - 20;
    const int b2 = bm >> 11;
    const int sbase = bm & (S_LEN - 1);
    short* dp = vT + (((size_t)(b2 * NKV + kvh2) * HD + d) * S_LEN) + sbase + half * 64;
#pragma unroll
    for (int c8 = 0; c8 < 8; c8++) {
      short vbuf[8];
#pragma unroll
      for (int j = 0; j < 8; j++) vbuf[j] = ep[half * 64 + c8 * 8 + j][d];
      *reinterpret_cast<int4*>(dp + c8 * 8) = *reinterpret_cast<int4*>(vbuf);
    }
  } else {
    // Q/K: per-row RMSNorm + partial RoPE (+gain for Q); 32 rows per wave.
    const float g = (mode == 2) ? gain[y] * QK_SCALE : 1.0f;
    short* dstbase = (mode == 2) ? Cq : Ck;
    const int head = (mode == 2) ? y : (y - 16);
    const int nh = (mode == 2) ? NH : NKV;
    const int i2 = lane & 31;
    const float inv = powf(10000.0f, -((float)(2 * i2) * (1.0f / 64.0f)));
    for (int j = 0; j < 32; j++) {
      const int rho = wave * 32 + j;
      const int token = bm + rho;
      const int s2 = token & (S_LEN - 1);
      const int b2 = token >> 11;
      float v0 = h2f(ep[rho][lane]);
      float v1 = h2f(ep[rho][lane + 64]);
      float ss = v0 * v0 + v1 * v1;
#pragma unroll
      for (int off = 1; off < 64; off <<= 1) ss += __shfl_xor(ss, off, 64);
      float scn = rsqrtf(ss * (1.0f / 128.0f) + 1.1920929e-07f);
      v0 *= scn;
      v1 *= scn;
      float f = (float)s2 * inv;
      float cs, sn;
      sincosf(f, &sn, &cs);
      float partner = __shfl_xor(v0, 32, 64);
      v0 = (lane < 32) ? (v0 * cs + partner * sn) : (v0 * cs - partner * sn);
      v0 *= g;
      v1 *= g;
      short* dp = dstbase + ((size_t)(b2 * nh + head) * S_LEN + s2) * HD;
      dp[lane] = f2h(v0);
      dp[lane + 64] = f2h(v1);
    }
  }
}

// ---------------------------------------------------------------------------
// Flash-style causal attention = R13 body + T13 defer-max (THR=8), verified.
// Block = 4 waves; wave = 16 queries; pair-in-block over BQ=64 sub-blocks
// (512 uniform blocks, 2/CU, lb(256,2)). In-loop int4 staging. XCD stream
// swizzle: strm=D&7 -> (b,kvh).
// ---------------------------------------------------------------------------
__global__ __launch_bounds__(256, 2) void attn_fwd(const short* __restrict__ qb,
                                                   const short* __restrict__ kb,
                                                   const short* __restrict__ vT,
                                                   short* __restrict__ out) {
  __shared__ __align__(16) short k_lds[64][136];
  __shared__ __align__(16) short vt_lds[144][72];
  __shared__ __align__(16) short p_lds[4][16][72];

  const int tid = threadIdx.x, wave = tid >> 6, lane = tid & 63;
  const int quad = lane >> 4, l16 = lane & 15;
  const int D = blockIdx.x;
  const int strm = D & 7;
  const int t = D >> 3;
  const int pj = t >> 2;
  const int b = strm >> 2;
  const int kvh = strm & 3;
  const int h = kvh * 4 + (t & 3);

  const short* kptr = kb + ((size_t)(b * NKV + kvh) * S_LEN) * HD;
  const short* vtp  = vT + ((size_t)(b * NKV + kvh) * HD) * S_LEN;

  const int kr = (tid >> 4), kc = (tid & 15) * 8;
  const int vr = (tid >> 3), vc = (tid & 7) * 8;

  {
    int r = 128 + (tid >> 4);
    int c = (tid & 15) * 4;
    short val = (r == 128) ? (short)0x3C00 : (short)0;
    short4 v4 = {val, val, val, val};
    *reinterpret_cast<short4*>(&vt_lds[r][c]) = v4;
  }

  for (int pass = 0; pass < 2; pass++) {
    const int qsub = pass ? (31 - pj) : pj;
    const int q0 = qsub * 64 + wave * 16;
    const short* qptr = qb + ((size_t)(b * NH + h) * S_LEN + q0) * HD;

    f16x8 qf[4];
#pragma unroll
    for (int st = 0; st < 4; st++)
      qf[st] = *reinterpret_cast<const f16x8*>(
          qptr + (size_t)l16 * HD + st * 32 + quad * 8);

    f32x4 o[9];
#pragma unroll
    for (int i = 0; i < 9; i++) o[i] = f32x4{0.f, 0.f, 0.f, 0.f};
    float m_i[4] = {NEG_SENT, NEG_SENT, NEG_SENT, NEG_SENT};

    const int ktiles = qsub + 1;
    for (int kt = 0; kt < ktiles; kt++) {
      const int kbase = kt * 64;
      __syncthreads();
#pragma unroll
      for (int i = 0; i < 4; i++)
        *reinterpret_cast<int4*>(&k_lds[kr + i * 16][kc]) =
            *reinterpret_cast<const int4*>(kptr + (size_t)(kbase + kr + i * 16) * HD + kc);
#pragma unroll
      for (int i = 0; i < 4; i++)
        *reinterpret_cast<int4*>(&vt_lds[vr + i * 32][vc]) =
            *reinterpret_cast<const int4*>(vtp + (size_t)(vr + i * 32) * S_LEN + kbase + vc);
      __syncthreads();

      f32x4 sc[4];
#pragma unroll
      for (int ct = 0; ct < 4; ct++) sc[ct] = f32x4{0.f, 0.f, 0.f, 0.f};
#pragma unroll
      for (int ct = 0; ct < 4; ct++) {
#pragma unroll
        for (int st = 0; st < 4; st++) {
          f16x8 kf = *reinterpret_cast<const f16x8*>(&k_lds[ct * 16 + l16][st * 32 + quad * 8]);
          sc[ct] = __builtin_amdgcn_mfma_f32_16x16x32_f16(qf[st], kf, sc[ct], 0, 0, 0);
        }
      }

      if (kbase + 63 > q0) {
#pragma unroll
        for (int ct = 0; ct < 4; ct++)
#pragma unroll
          for (int r = 0; r < 4; r++) {
            int qrow = q0 + quad * 4 + r;
            int col = kbase + ct * 16 + l16;
            sc[ct][r] = (col <= qrow) ? sc[ct][r] : NEG_SENT;
          }
      }

      float cand[4];
#pragma unroll
      for (int r = 0; r < 4; r++)
        cand[r] = fmaxf(fmaxf(sc[0][r], sc[1][r]), fmaxf(sc[2][r], sc[3][r]));
#pragma unroll
      for (int off = 1; off < 16; off <<= 1)
#pragma unroll
        for (int r = 0; r < 4; r++)
          cand[r] = fmaxf(cand[r], __shfl_xor(cand[r], off, 64));

      bool ch = (cand[0] > m_i[0] + RESCALE_THR) | (cand[1] > m_i[1] + RESCALE_THR) |
                (cand[2] > m_i[2] + RESCALE_THR) | (cand[3] > m_i[3] + RESCALE_THR);
      if (__any(ch)) {
        float alpha[4];
#pragma unroll
        for (int r = 0; r < 4; r++) {
          float mn = fmaxf(m_i[r], cand[r]);
          alpha[r] = __expf(m_i[r] - mn);
          m_i[r] = mn;
        }
#pragma unroll
        for (int nt = 0; nt < 9; nt++)
#pragma unroll
          for (int r = 0; r < 4; r++) o[nt][r] *= alpha[r];
      }

#pragma unroll
      for (int ct = 0; ct < 4; ct++)
#pragma unroll
        for (int r = 0; r < 4; r++) {
          float p = __expf(sc[ct][r] - m_i[r]);
          p_lds[wave][quad * 4 + r][ct * 16 + l16] = f2h(p);
        }

      f16x8 pf0 = *reinterpret_cast<const f16x8*>(&p_lds[wave][l16][quad * 8]);
      f16x8 pf1 = *reinterpret_cast<const f16x8*>(&p_lds[wave][l16][32 + quad * 8]);
#pragma unroll
      for (int nt = 0; nt < 9; nt++) {
        f16x8 vf0 = *reinterpret_cast<const f16x8*>(&vt_lds[nt * 16 + l16][quad * 8]);
        f16x8 vf1 = *reinterpret_cast<const f16x8*>(&vt_lds[nt * 16 + l16][32 + quad * 8]);
        o[nt] = __builtin_amdgcn_mfma_f32_16x16x32_f16(pf0, vf0, o[nt], 0, 0, 0);
        o[nt] = __builtin_amdgcn_mfma_f32_16x16x32_f16(pf1, vf1, o[nt], 0, 0, 0);
      }
    }

    float inv_l[4];
#pragma unroll
    for (int r = 0; r < 4; r++) {
      float l = __shfl(o[8][r], lane & 48, 64);
      inv_l[r] = 1.0f / fmaxf(l, 1e-20f);
    }
#pragma unroll
    for (int nt = 0; nt < 8; nt++)
#pragma unroll
      for (int r = 0; r < 4; r++) {
        int srow = q0 + quad * 4 + r;
        int dcol = nt * 16 + l16;
        out[((size_t)(b * S_LEN + srow)) * DMODEL + h * HD + dcol] =
            f2h(o[nt][r] * inv_l[r]);
      }
  }
}

extern "C" void kernel_launch(void* const* d_in, const int* in_sizes, int n_in,
                              void* d_out, int out_size, void* d_ws, size_t ws_size,
                              hipStream_t stream) {
  const float* x      = (const float*)d_in[0];
  const float* q_w    = (const float*)d_in[1];
  const float* k_w    = (const float*)d_in[2];
  const float* v_w    = (const float*)d_in[3];
  const float* out_w  = (const float*)d_in[4];
  const float* q_gain = (const float*)d_in[5];
  float* out = (float*)d_out;

  short* xb   = (short*)d_ws;                    // 8M  (16MB)
  short* wqb  = xb   + (size_t)8 * 1024 * 1024;  // 4M
  short* wkb  = wqb  + (size_t)4 * 1024 * 1024;  // 1M
  short* wvb  = wkb  + (size_t)1 * 1024 * 1024;  // 1M
  short* wob  = wvb  + (size_t)1 * 1024 * 1024;  // 4M
  short* attn = wob  + (size_t)4 * 1024 * 1024;  // 8M (attention output, token-major)
  short* qbuf = attn + (size_t)8 * 1024 * 1024;  // 8M
  short* kbuf = qbuf + (size_t)8 * 1024 * 1024;  // 2M
  short* vT   = kbuf + (size_t)2 * 1024 * 1024;  // 2M ([b][kv][dim][seq])

  dim3 blk(256);
  // one fused convert launch: 4718592 float4 / 256 = 18432 blocks
  f32_to_f16_all<<<18432, blk, 0, stream>>>(x, q_w, k_w, v_w, out_w,
                                            xb, wqb, wkb, wvb, wob);

  // Q/K/V projections + fused norm/rope/gain/transpose epilogue
  gemm_qkv<<<dim3(32, 24), blk, 0, stream>>>(xb, wqb, wkb, wvb,
                                             qbuf, kbuf, vT, q_gain, 2048);

  attn_fwd<<<dim3(512), blk, 0, stream>>>(qbuf, kbuf, vT, attn);

  gemm_bt<true><<<dim3(32, 16), blk, 0, stream>>>(attn, wob, out, 2048, 2048);
}